// Round 1
// baseline (1633.767 us; speedup 1.0000x reference)
//
#include <hip/hip_runtime.h>
#include <math.h>

// Problem constants (B=4, H=8, L=2048, DK=DV=32)
#define LQ   2048
#define DKD  32
#define TQ   32      // q rows per block
#define KT   128     // k per tile
#define NT   (LQ / KT)   // 16 tiles
#define KSTR 36      // padded row stride for Kt/Vt/Qs (floats) -> conflict-free b128
#define PSTR 132     // padded row stride for Pt (floats)
#define CSTR 33      // ctx-union row stride

__global__ __launch_bounds__(256, 2)
void sdpa_fused(const float* __restrict__ Q,
                const float* __restrict__ K,
                const float* __restrict__ V,
                const int*   __restrict__ mask,
                const float* __restrict__ res,
                float* __restrict__ outCtx,
                float* __restrict__ outSc)
{
    __shared__ float Kt[KT * KSTR];   // 18432 B
    __shared__ float Vt[KT * KSTR];   // 18432 B
    __shared__ float Pt[TQ * PSTR];   // 16896 B ; reused as ctx[4][32][33] at the end
    __shared__ float Qs[TQ * KSTR];   //  4608 B
    __shared__ float mred[4 * TQ];
    __shared__ float lred[4 * TQ];

    const int t    = threadIdx.x;
    const int g    = t >> 6;          // wave 0..3 (owns k-quarter g)
    const int lane = t & 63;
    const int qg   = lane >> 3;       // 0..7
    const int kg   = lane & 7;        // 0..7 (= dg in PV phase)

    const int bx = blockIdx.x;
    const int bh = bx >> 6;           // 0..31
    const int qt = bx & 63;           // 0..63

    const long rowQ0 = (long)bh * LQ + (long)qt * TQ;

    // ---- stage Q tile (32x32) ----
    {
        int q  = t >> 3;
        int d4 = (t & 7) << 2;
        float4 qv = *(const float4*)(Q + (rowQ0 + q) * DKD + d4);
        *(float4*)(Qs + q * KSTR + d4) = qv;
    }

    // per-thread online-softmax state for rows q = qg + 8*i (per-wave k-quarter)
    float m[4], l[4], acc[4][4];
    #pragma unroll
    for (int i = 0; i < 4; i++) {
        m[i] = -1e30f; l[i] = 0.f;
        acc[i][0] = acc[i][1] = acc[i][2] = acc[i][3] = 0.f;
    }

    const float scale = 0.17677669529663687f;  // 1/sqrt(32)

    for (int kt = 0; kt < NT; kt++) {
        __syncthreads();  // prev-tile PV done (iter0: also covers Qs staging)

        // ---- stage K,V tile (global -> regs) ----
        const long k0g = (long)bh * LQ + (long)kt * KT;
        float4 kst[4], vst[4];
        #pragma unroll
        for (int u = 0; u < 4; u++) {
            int f  = t + 256 * u;         // 0..1023 float4 slots
            int kr = f >> 3;
            int d4 = (f & 7) << 2;
            kst[u] = *(const float4*)(K + (k0g + kr) * DKD + d4);
            vst[u] = *(const float4*)(V + (k0g + kr) * DKD + d4);
        }

        // ---- issue res/mask loads EARLY (consumed after the FMA block) ----
        float rv[4][4]; int mv[4][4];
        const long colBase = (long)kt * KT + g * 32 + kg;
        #pragma unroll
        for (int i = 0; i < 4; i++) {
            const long rb = (rowQ0 + qg + 8*i) * (long)LQ + colBase;
            #pragma unroll
            for (int j = 0; j < 4; j++) {
                rv[i][j] = res[rb + 8*j];
                mv[i][j] = mask[rb + 8*j];
            }
        }

        // ---- regs -> LDS ----
        #pragma unroll
        for (int u = 0; u < 4; u++) {
            int f  = t + 256 * u;
            int kr = f >> 3;
            int d4 = (f & 7) << 2;
            *(float4*)(Kt + kr * KSTR + d4) = kst[u];
            *(float4*)(Vt + kr * KSTR + d4) = vst[u];
        }
        __syncthreads();

        // ---- QK^T: 4q x 4k micro-tile, k = g*32 + kg + 8*j ----
        float S[4][4];
        #pragma unroll
        for (int i = 0; i < 4; i++) { S[i][0]=S[i][1]=S[i][2]=S[i][3]=0.f; }
        #pragma unroll
        for (int s = 0; s < 8; s++) {
            float4 qf[4], kf[4];
            #pragma unroll
            for (int i = 0; i < 4; i++)
                qf[i] = *(const float4*)(Qs + (qg + 8*i) * KSTR + 4*s);
            #pragma unroll
            for (int j = 0; j < 4; j++)
                kf[j] = *(const float4*)(Kt + (g*32 + kg + 8*j) * KSTR + 4*s);
            #pragma unroll
            for (int i = 0; i < 4; i++) {
                #pragma unroll
                for (int j = 0; j < 4; j++) {
                    S[i][j] += qf[i].x * kf[j].x;
                    S[i][j] += qf[i].y * kf[j].y;
                    S[i][j] += qf[i].z * kf[j].z;
                    S[i][j] += qf[i].w * kf[j].w;
                }
            }
        }

        // ---- epilogue: scale + res, mask, emit scores ----
        #pragma unroll
        for (int i = 0; i < 4; i++) {
            const long rb = (rowQ0 + qg + 8*i) * (long)LQ + colBase;
            #pragma unroll
            for (int j = 0; j < 4; j++) {
                float sv = S[i][j] * scale + rv[i][j];
                sv = mv[i][j] ? -1e9f : sv;
                S[i][j] = sv;
                outSc[rb + 8*j] = sv;
            }
        }

        // ---- per-wave online softmax over this wave's 32 k ----
        #pragma unroll
        for (int i = 0; i < 4; i++) {
            float mloc = fmaxf(fmaxf(S[i][0], S[i][1]), fmaxf(S[i][2], S[i][3]));
            mloc = fmaxf(mloc, __shfl_xor(mloc, 1));
            mloc = fmaxf(mloc, __shfl_xor(mloc, 2));
            mloc = fmaxf(mloc, __shfl_xor(mloc, 4));
            float mn = fmaxf(m[i], mloc);
            float al = __expf(m[i] - mn);
            m[i] = mn;
            float ps = 0.f;
            #pragma unroll
            for (int j = 0; j < 4; j++) {
                float p = __expf(S[i][j] - mn);
                Pt[(qg + 8*i) * PSTR + g*32 + kg + 8*j] = p;
                ps += p;
            }
            ps += __shfl_xor(ps, 1);
            ps += __shfl_xor(ps, 2);
            ps += __shfl_xor(ps, 4);
            l[i] = l[i] * al + ps;
            acc[i][0] *= al; acc[i][1] *= al; acc[i][2] *= al; acc[i][3] *= al;
        }

        // ---- PV over own quarter (same-wave Pt round trip, no barrier) ----
        #pragma unroll
        for (int s2 = 0; s2 < 8; s2++) {
            const int kk = g*32 + 4*s2;
            float4 pf[4];
            #pragma unroll
            for (int i = 0; i < 4; i++)
                pf[i] = *(const float4*)(Pt + (qg + 8*i) * PSTR + kk);
            #pragma unroll
            for (int j2 = 0; j2 < 4; j2++) {
                float4 vf = *(const float4*)(Vt + (kk + j2) * KSTR + 4*kg);
                #pragma unroll
                for (int i = 0; i < 4; i++) {
                    float p = (j2 == 0) ? pf[i].x : (j2 == 1) ? pf[i].y
                            : (j2 == 2) ? pf[i].z : pf[i].w;
                    acc[i][0] += p * vf.x;
                    acc[i][1] += p * vf.y;
                    acc[i][2] += p * vf.z;
                    acc[i][3] += p * vf.w;
                }
            }
        }
    }

    // ---- merge the 4 per-wave (m, l, acc) states ----
    __syncthreads();   // everyone done with Pt as P-buffer
    #pragma unroll
    for (int i = 0; i < 4; i++) {
        float* c = Pt + g * (TQ * CSTR) + (qg + 8*i) * CSTR + 4*kg;
        c[0] = acc[i][0]; c[1] = acc[i][1]; c[2] = acc[i][2]; c[3] = acc[i][3];
        if (kg == 0) {
            mred[g * TQ + qg + 8*i] = m[i];
            lred[g * TQ + qg + 8*i] = l[i];
        }
    }
    __syncthreads();
    {
        int q  = t >> 3;
        int d4 = (t & 7) << 2;
        float m0 = mred[q], m1 = mred[TQ + q], m2 = mred[2*TQ + q], m3 = mred[3*TQ + q];
        float mm = fmaxf(fmaxf(m0, m1), fmaxf(m2, m3));
        float w0 = __expf(m0 - mm), w1 = __expf(m1 - mm);
        float w2 = __expf(m2 - mm), w3 = __expf(m3 - mm);
        float lt = lred[q]*w0 + lred[TQ+q]*w1 + lred[2*TQ+q]*w2 + lred[3*TQ+q]*w3;
        float inv = 1.0f / lt;
        const float* c0 = Pt + 0*(TQ*CSTR) + q*CSTR + d4;
        const float* c1 = Pt + 1*(TQ*CSTR) + q*CSTR + d4;
        const float* c2 = Pt + 2*(TQ*CSTR) + q*CSTR + d4;
        const float* c3 = Pt + 3*(TQ*CSTR) + q*CSTR + d4;
        float4 o;
        o.x = (c0[0]*w0 + c1[0]*w1 + c2[0]*w2 + c3[0]*w3) * inv;
        o.y = (c0[1]*w0 + c1[1]*w1 + c2[1]*w2 + c3[1]*w3) * inv;
        o.z = (c0[2]*w0 + c1[2]*w1 + c2[2]*w2 + c3[2]*w3) * inv;
        o.w = (c0[3]*w0 + c1[3]*w1 + c2[3]*w2 + c3[3]*w3) * inv;
        *(float4*)(outCtx + (rowQ0 + q) * DKD + d4) = o;
    }
}

extern "C" void kernel_launch(void* const* d_in, const int* in_sizes, int n_in,
                              void* d_out, int out_size, void* d_ws, size_t ws_size,
                              hipStream_t stream) {
    // setup_inputs order: Q, K, V, attn_mask, res_att
    const float* Q    = (const float*)d_in[0];
    const float* K    = (const float*)d_in[1];
    const float* V    = (const float*)d_in[2];
    const int*   mask = (const int*)d_in[3];
    const float* res  = (const float*)d_in[4];
    float* outCtx = (float*)d_out;                                  // [4,8,2048,32]
    float* outSc  = (float*)d_out + (size_t)4 * 8 * 2048 * 32;      // [4,8,2048,2048]
    sdpa_fused<<<dim3(2048), dim3(256), 0, stream>>>(Q, K, V, mask, res, outCtx, outSc);
}